// Round 15
// baseline (613.247 us; speedup 1.0000x reference)
//
#include <hip/hip_runtime.h>
#include <hip/hip_bf16.h>

// RGCN layer: out = x@W_self + b_self + sum_t [ mean_t(x[src]) @ W[t] + (deg_t>0)*b[t] ]
// v10 (resubmit; prior round hit GPUAcquisitionTimeout, never measured):
//      delete the CSR build. v9 measured: k_fused back at 207us (v3-identical), prep
//      chain 331us and INSENSITIVE to 4x instruction reduction -> atomic/latency
//      bound. Restructure: fixed-capacity buckets eid[(t*N+d)*CAP + rank], written
//      directly in the count kernel from atomicAdd's return (CAP=32 >> max degree
//      ~15 for Poisson(2.5); guarded). Removes k_offsets + k_scatter + rank array
//      (2 launches, ~30MB traffic). k_zero -> hipMemsetAsync. k_fused: only the
//      bucket base computation changes ((pass*N+node)*CAP vs offs read).
//      Bucket mode needs ~157MB ws -> runtime check, full CSR fallback (v9 path).

namespace {

constexpr int N  = 200000;  // nodes
constexpr int T  = 4;       // etypes
constexpr int E  = 500000;  // edges per etype
constexpr int D  = 128;     // d_in == d_out
constexpr int NT = 64;      // nodes per block tile
constexpr int AS = 136;     // padded LDS row stride (bf16): 2-way bank alias only (free)
constexpr int CAP = 32;     // bucket capacity (max degree ~15 at Poisson 2.5)

constexpr int CNT_B = (T * E / 4 + 255) / 256;      // 1954 (4 edges/thread)
constexpr int PX_B  = (N * D / 8) / 256;            // 12500 (exact)
constexpr int PW_B  = (5 * D * D / 8 + 255) / 256;  // 40

typedef __bf16 bf16x8 __attribute__((ext_vector_type(8)));
typedef float  f32x4  __attribute__((ext_vector_type(4)));

// ---------- bucket-mode prep: count + direct bucket scatter | x->bf16 | W pack
__global__ void k_prep_bkt(const int* __restrict__ dst, const int* __restrict__ src,
                           int* __restrict__ cnt, int* __restrict__ eid,
                           const float* __restrict__ x, __bf16* __restrict__ xb,
                           const float* __restrict__ W,
                           const float* __restrict__ Wself, __bf16* __restrict__ wt) {
  const int bid = blockIdx.x;
  const int tid = threadIdx.x;
  if (bid < CNT_B) {
    int i0 = (bid * 256 + tid) * 4;
    if (i0 < T * E) {
      int t = i0 / E;                  // pack never straddles etype (E%4==0)
      int4 d = *(const int4*)(dst + i0);
      int4 s = *(const int4*)(src + i0);
      int r;
      r = atomicAdd(&cnt[t * N + d.x], 1);
      if (r < CAP) eid[(t * N + d.x) * CAP + r] = s.x;
      r = atomicAdd(&cnt[t * N + d.y], 1);
      if (r < CAP) eid[(t * N + d.y) * CAP + r] = s.y;
      r = atomicAdd(&cnt[t * N + d.z], 1);
      if (r < CAP) eid[(t * N + d.z) * CAP + r] = s.z;
      r = atomicAdd(&cnt[t * N + d.w], 1);
      if (r < CAP) eid[(t * N + d.w) * CAP + r] = s.w;
    }
  } else if (bid < CNT_B + PX_B) {
    int i = (bid - CNT_B) * 256 + tid;  // one per 8 floats
    if (i < N * D / 8) {
      const float4* xs = (const float4*)(x + i * 8);
      float4 a = xs[0], c = xs[1];
      bf16x8 v;
      v[0] = (__bf16)a.x; v[1] = (__bf16)a.y; v[2] = (__bf16)a.z; v[3] = (__bf16)a.w;
      v[4] = (__bf16)c.x; v[5] = (__bf16)c.y; v[6] = (__bf16)c.z; v[7] = (__bf16)c.w;
      *(bf16x8*)(xb + i * 8) = v;
    }
  } else {
    int i = (bid - CNT_B - PX_B) * 256 + tid;  // one per 8 wt elems
    if (i < 5 * D * D / 8) {
      int base = i * 8;
      int p = base >> 14, rem = base & 16383;
      int n = rem >> 7, k0 = rem & 127;
      const float* Wsrc = (p < 4) ? (W + (size_t)p * D * D) : Wself;  // [k][n]
      bf16x8 v;
#pragma unroll
      for (int j = 0; j < 8; ++j) v[j] = (__bf16)Wsrc[(k0 + j) * D + n];
      *(bf16x8*)(wt + base) = v;
    }
  }
}

// ---------- CSR-fallback kernels (v9, proven) ----------
template <bool XB>
__global__ void k_prep(const int* __restrict__ dst, int* __restrict__ cnt,
                       int* __restrict__ rank, const float* __restrict__ x,
                       __bf16* __restrict__ xb, const float* __restrict__ W,
                       const float* __restrict__ Wself, __bf16* __restrict__ wt) {
  const int bid = blockIdx.x;
  const int tid = threadIdx.x;
  if (bid < CNT_B) {
    int i0 = (bid * 256 + tid) * 4;
    if (i0 < T * E) {
      int t = i0 / E;
      int4 d = *(const int4*)(dst + i0);
      int4 r;
      r.x = atomicAdd(&cnt[t * N + d.x], 1);
      r.y = atomicAdd(&cnt[t * N + d.y], 1);
      r.z = atomicAdd(&cnt[t * N + d.z], 1);
      r.w = atomicAdd(&cnt[t * N + d.w], 1);
      *(int4*)(rank + i0) = r;
    }
  } else if (XB && bid < CNT_B + PX_B) {
    int i = (bid - CNT_B) * 256 + tid;
    if (i < N * D / 8) {
      const float4* xs = (const float4*)(x + i * 8);
      float4 a = xs[0], c = xs[1];
      bf16x8 v;
      v[0] = (__bf16)a.x; v[1] = (__bf16)a.y; v[2] = (__bf16)a.z; v[3] = (__bf16)a.w;
      v[4] = (__bf16)c.x; v[5] = (__bf16)c.y; v[6] = (__bf16)c.z; v[7] = (__bf16)c.w;
      *(bf16x8*)(xb + i * 8) = v;
    }
  } else {
    int i = (bid - CNT_B - (XB ? PX_B : 0)) * 256 + tid;
    if (i < 5 * D * D / 8) {
      int base = i * 8;
      int p = base >> 14, rem = base & 16383;
      int n = rem >> 7, k0 = rem & 127;
      const float* Wsrc = (p < 4) ? (W + (size_t)p * D * D) : Wself;
      bf16x8 v;
#pragma unroll
      for (int j = 0; j < 8; ++j) v[j] = (__bf16)Wsrc[(k0 + j) * D + n];
      *(bf16x8*)(wt + base) = v;
    }
  }
}

__global__ void k_offsets(const int* __restrict__ cnt, int* __restrict__ offs,
                          int* __restrict__ cursor) {
  __shared__ int s[256];
  __shared__ int base;
  int tid = threadIdx.x;
  int i = blockIdx.x * 256 + tid;
  int c = (i < T * N) ? cnt[i] : 0;
  s[tid] = c;
  __syncthreads();
  for (int d = 1; d < 256; d <<= 1) {
    int v = (tid >= d) ? s[tid - d] : 0;
    __syncthreads();
    s[tid] += v;
    __syncthreads();
  }
  if (tid == 255) base = atomicAdd(cursor, s[255]);
  __syncthreads();
  if (i < T * N) offs[i] = base + s[tid] - c;  // exclusive
}

__global__ void k_scatter(const int* __restrict__ src, const int* __restrict__ dst,
                          const int* __restrict__ offs, const int* __restrict__ rank,
                          int* __restrict__ eid) {
  int i0 = (blockIdx.x * 256 + threadIdx.x) * 4;
  if (i0 >= T * E) return;
  const int tb = (i0 / E) * N;
  int4 s = *(const int4*)(src + i0);
  int4 d = *(const int4*)(dst + i0);
  int4 r = *(const int4*)(rank + i0);
  eid[offs[tb + d.x] + r.x] = s.x;
  eid[offs[tb + d.y] + r.y] = s.y;
  eid[offs[tb + d.z] + r.z] = s.z;
  eid[offs[tb + d.w] + r.w] = s.w;
}

// ---------- fused aggregate + bf16 MFMA GEMM (v3 core; BKT changes base calc only)
// 256 threads (4 waves), 64-node tile. LDS 52224 B -> 3 blocks/CU. VGPR 76 proven.
template <bool XB, bool BKT>
__global__ __launch_bounds__(256, 3) void k_fused(
    const float* __restrict__ x, const __bf16* __restrict__ xb,
    const __bf16* __restrict__ wt, const float* __restrict__ b,
    const float* __restrict__ bself, const int* __restrict__ cnt,
    const int* __restrict__ offs, const int* __restrict__ eid,
    float* __restrict__ out) {
  __shared__ __align__(16) __bf16 a_s[NT * AS];
  __shared__ __align__(16) __bf16 w_s[D * AS];

  const int tid  = threadIdx.x;
  const int nb   = blockIdx.x * NT;
  const int wv   = tid >> 6;
  const int lane = tid & 63;
  const int quad = lane >> 4;
  const int l16  = lane & 15;
  const int ln   = tid >> 2;   // staging node 0..63
  const int q    = tid & 3;    // staging k-quarter: k = q*32 .. q*32+31

  f32x4 acc[8];
#pragma unroll
  for (int ct = 0; ct < 8; ++ct) acc[ct] = (f32x4){0.f, 0.f, 0.f, 0.f};

  for (int pass = 0; pass < 5; ++pass) {
    const bool self = (pass == 4);

    // ---- stage w_s (issue first; overlaps gather latency)
    {
      const __bf16* wsrc = wt + pass * D * D;
#pragma unroll
      for (int c = 0; c < 8; ++c) {
        int idx  = c * 256 + tid;
        int row  = idx >> 4;
        int col8 = (idx & 15) * 8;
        *(bf16x8*)(w_s + row * AS + col8) = *(const bf16x8*)(wsrc + row * D + col8);
      }
    }

    // ---- stage a_s: mean-aggregated features (skipped for self-pass when XB)
    if (!(XB && self)) {
      float r[32];
#pragma unroll
      for (int i = 0; i < 32; ++i) r[i] = 0.f;
      const int node = nb + ln;
      if (self) {  // only reached when !XB
        const float4* xr = (const float4*)(x + node * D + q * 32);
#pragma unroll
        for (int i = 0; i < 8; ++i) {
          float4 v = xr[i];
          r[4 * i] = v.x; r[4 * i + 1] = v.y; r[4 * i + 2] = v.z; r[4 * i + 3] = v.w;
        }
      } else {
        const int deg  = cnt[pass * N + node];
        const int base = BKT ? (pass * N + node) * CAP : offs[pass * N + node];
        int nxt = (deg > 0) ? eid[base] : 0;
        for (int e = 0; e < deg; ++e) {
          const int sidx = nxt;
          nxt = eid[base + e + 1];  // prefetch; slack guaranteed (CAP pad / rank array)
          if (XB) {
            const bf16x8* xr = (const bf16x8*)(xb + sidx * D + q * 32);
            bf16x8 v0 = xr[0], v1 = xr[1], v2 = xr[2], v3 = xr[3];
#pragma unroll
            for (int j = 0; j < 8; ++j) {
              r[j]      += (float)v0[j];
              r[8 + j]  += (float)v1[j];
              r[16 + j] += (float)v2[j];
              r[24 + j] += (float)v3[j];
            }
          } else {
            const float4* xr = (const float4*)(x + sidx * D + q * 32);
#pragma unroll
            for (int i = 0; i < 8; ++i) {
              float4 v = xr[i];
              r[4 * i] += v.x; r[4 * i + 1] += v.y;
              r[4 * i + 2] += v.z; r[4 * i + 3] += v.w;
            }
          }
        }
        const float inv = (deg > 0) ? (1.0f / (float)deg) : 0.0f;
#pragma unroll
        for (int i = 0; i < 32; ++i) r[i] *= inv;
      }
      __bf16* arow = a_s + ln * AS + q * 32;
#pragma unroll
      for (int g = 0; g < 4; ++g) {
        bf16x8 v;
#pragma unroll
        for (int j = 0; j < 8; ++j) v[j] = (__bf16)r[8 * g + j];
        *(bf16x8*)(arow + g * 8) = v;
      }
    }
    __syncthreads();

    // ---- MFMA: acc[16 x 128 per wave] += A @ W^T-layout
#pragma unroll
    for (int ks = 0; ks < 4; ++ks) {
      bf16x8 af;
      if (XB && self) {
        af = *(const bf16x8*)(xb + (nb + 16 * wv + l16) * D + ks * 32 + quad * 8);
      } else {
        af = *(const bf16x8*)(a_s + (16 * wv + l16) * AS + ks * 32 + quad * 8);
      }
#pragma unroll
      for (int ct = 0; ct < 8; ++ct) {
        bf16x8 bfr = *(const bf16x8*)(w_s + (16 * ct + l16) * AS + ks * 32 + quad * 8);
        acc[ct] = __builtin_amdgcn_mfma_f32_16x16x32_bf16(af, bfr, acc[ct], 0, 0, 0);
      }
    }

    // ---- bias: b[t] gated on deg>0 per output row; b_self unconditional.
    {
      const float* bt = self ? bself : (b + pass * D);
      bool rowon[4];
#pragma unroll
      for (int r = 0; r < 4; ++r) {
        rowon[r] = self ? true : (cnt[pass * N + nb + 16 * wv + quad * 4 + r] > 0);
      }
#pragma unroll
      for (int ct = 0; ct < 8; ++ct) {
        float bv = bt[16 * ct + l16];
#pragma unroll
        for (int r = 0; r < 4; ++r)
          if (rowon[r]) acc[ct][r] += bv;
      }
    }
    if (pass < 4) __syncthreads();  // guard LDS overwrite by next pass
  }

  // ---- epilogue
#pragma unroll
  for (int ct = 0; ct < 8; ++ct) {
#pragma unroll
    for (int r = 0; r < 4; ++r) {
      out[(nb + 16 * wv + quad * 4 + r) * D + 16 * ct + l16] = acc[ct][r];
    }
  }
}

}  // namespace

extern "C" void kernel_launch(void* const* d_in, const int* in_sizes, int n_in,
                              void* d_out, int out_size, void* d_ws, size_t ws_size,
                              hipStream_t stream) {
  const float* x     = (const float*)d_in[0];
  const float* W     = (const float*)d_in[1];
  const float* b     = (const float*)d_in[2];
  const float* Wself = (const float*)d_in[3];
  const float* bself = (const float*)d_in[4];
  const int*   src   = (const int*)d_in[5];
  const int*   dst   = (const int*)d_in[6];
  float* out = (float*)d_out;

  // bucket ws: cnt[T*N] | eid[T*N*CAP + 16] | wt bf16[5*D*D] | xb bf16[N*D]
  const size_t need_bkt =
      (size_t)(T * N + T * N * CAP + 16) * 4 + (size_t)5 * D * D * 2 +
      (size_t)N * D * 2;  // ~157 MB
  // CSR ws (v9): cnt[T*N] | cursor[4] | offs[T*N] | eid[T*E] | rank[T*E] | wt | xb
  const size_t need_xb =
      (size_t)(T * N + 4 + T * N + T * E + T * E) * 4 + (size_t)5 * D * D * 2 +
      (size_t)N * D * 2;  // ~74 MB

  int* cnt = (int*)d_ws;

  if (ws_size >= need_bkt) {
    int* eid    = cnt + T * N;
    __bf16* wt  = (__bf16*)(eid + T * N * CAP + 16);
    __bf16* xb  = wt + 5 * D * D;
    hipMemsetAsync(cnt, 0, (size_t)T * N * 4, stream);
    k_prep_bkt<<<CNT_B + PX_B + PW_B, 256, 0, stream>>>(dst, src, cnt, eid, x, xb,
                                                        W, Wself, wt);
    k_fused<true, true><<<N / NT, 256, 0, stream>>>(x, xb, wt, b, bself, cnt,
                                                    nullptr, eid, out);
    return;
  }

  // ---- CSR fallback (v9 path) ----
  int* cursor = cnt + T * N;
  int* offs   = cursor + 4;
  int* eid    = offs + T * N;
  int* rank   = eid + T * E;   // rank doubles as slack for eid's +1 prefetch
  __bf16* wt  = (__bf16*)(rank + T * E);
  __bf16* xb  = wt + 5 * D * D;
  const bool use_xb = ws_size >= need_xb;

  hipMemsetAsync(cnt, 0, (size_t)(T * N + 4) * 4, stream);
  if (use_xb) {
    k_prep<true><<<CNT_B + PX_B + PW_B, 256, 0, stream>>>(dst, cnt, rank, x, xb,
                                                          W, Wself, wt);
  } else {
    k_prep<false><<<CNT_B + PW_B, 256, 0, stream>>>(dst, cnt, rank, x, xb, W,
                                                    Wself, wt);
  }
  k_offsets<<<(T * N + 255) / 256, 256, 0, stream>>>(cnt, offs, cursor);
  k_scatter<<<CNT_B, 256, 0, stream>>>(src, dst, offs, rank, eid);
  if (use_xb) {
    k_fused<true, false><<<N / NT, 256, 0, stream>>>(x, xb, wt, b, bself, cnt,
                                                     offs, eid, out);
  } else {
    k_fused<false, false><<<N / NT, 256, 0, stream>>>(x, xb, wt, b, bself, cnt,
                                                      offs, eid, out);
  }
}

// Round 16
// 538.124 us; speedup vs baseline: 1.1396x; 1.1396x over previous
//
#include <hip/hip_runtime.h>
#include <hip/hip_bf16.h>

// RGCN layer: out = x@W_self + b_self + sum_t [ mean_t(x[src]) @ W[t] + (deg_t>0)*b[t] ]
// v11: revert v10's buckets (prep_bkt measured 270us, VALU 0.6% @ 83% occ: atomic
//      latency + dependent random store). Base = v9 CSR (539us). Two changes:
//      (1) 8x-sharded counters cnt_s[bid&7][t*N+d]: round-robin block->XCD dispatch
//          keeps each shard's 3.2MB in one XCD's L2 -> ~8x less same-line atomic
//          conflict + no cross-XCD ping-pong. rank packs shard in bits 28-30;
//          k_offsets emits per-shard bases sbase[8][T*N]; k_scatter unpacks.
//          (Any block->shard map is correct; XCD alignment only affects speed.)
//      (2) k_fused gather: 2-deep software pipeline (load edge e+1's rows, guarded,
//          before accumulating edge e). VALU 26%/stall 70% said compiler doesn't.
//      Fallback (small ws): exact v9 path.

namespace {

constexpr int N  = 200000;
constexpr int T  = 4;
constexpr int E  = 500000;
constexpr int D  = 128;
constexpr int NT = 64;
constexpr int AS = 136;     // padded LDS row stride (bf16)
constexpr int TN = T * N;

constexpr int CNT_B = (T * E / 4 + 255) / 256;      // 1954 (4 edges/thread)
constexpr int PX_B  = (N * D / 8) / 256;            // 12500
constexpr int PW_B  = (5 * D * D / 8 + 255) / 256;  // 40

typedef __bf16 bf16x8 __attribute__((ext_vector_type(8)));
typedef float  f32x4  __attribute__((ext_vector_type(4)));

// Fused: edge count (sharded when SH) | x fp32->bf16 | W^T pack to bf16.
template <bool SH>
__global__ void k_prep(const int* __restrict__ dst, int* __restrict__ cnt_s,
                       int* __restrict__ rank, const float* __restrict__ x,
                       __bf16* __restrict__ xb, const float* __restrict__ W,
                       const float* __restrict__ Wself, __bf16* __restrict__ wt) {
  const int bid = blockIdx.x;
  const int tid = threadIdx.x;
  if (bid < CNT_B) {
    int i0 = (bid * 256 + tid) * 4;
    if (i0 < T * E) {
      int t = i0 / E;  // pack never straddles etype (E%4==0)
      int4 d = *(const int4*)(dst + i0);
      int4 r;
      if (SH) {
        const int sh = bid & 7;
        int* mc = cnt_s + sh * TN + t * N;
        r.x = atomicAdd(&mc[d.x], 1) | (sh << 28);
        r.y = atomicAdd(&mc[d.y], 1) | (sh << 28);
        r.z = atomicAdd(&mc[d.z], 1) | (sh << 28);
        r.w = atomicAdd(&mc[d.w], 1) | (sh << 28);
      } else {
        int* mc = cnt_s + t * N;
        r.x = atomicAdd(&mc[d.x], 1);
        r.y = atomicAdd(&mc[d.y], 1);
        r.z = atomicAdd(&mc[d.z], 1);
        r.w = atomicAdd(&mc[d.w], 1);
      }
      *(int4*)(rank + i0) = r;
    }
  } else if (bid < CNT_B + PX_B) {
    int i = (bid - CNT_B) * 256 + tid;  // one per 8 floats
    if (i < N * D / 8) {
      const float4* xs = (const float4*)(x + i * 8);
      float4 a = xs[0], c = xs[1];
      bf16x8 v;
      v[0] = (__bf16)a.x; v[1] = (__bf16)a.y; v[2] = (__bf16)a.z; v[3] = (__bf16)a.w;
      v[4] = (__bf16)c.x; v[5] = (__bf16)c.y; v[6] = (__bf16)c.z; v[7] = (__bf16)c.w;
      *(bf16x8*)(xb + i * 8) = v;
    }
  } else {
    int i = (bid - CNT_B - PX_B) * 256 + tid;  // one per 8 wt elems
    if (i < 5 * D * D / 8) {
      int base = i * 8;
      int p = base >> 14, rem = base & 16383;
      int n = rem >> 7, k0 = rem & 127;
      const float* Wsrc = (p < 4) ? (W + (size_t)p * D * D) : Wself;  // [k][n]
      bf16x8 v;
#pragma unroll
      for (int j = 0; j < 8; ++j) v[j] = (__bf16)Wsrc[(k0 + j) * D + n];
      *(bf16x8*)(wt + base) = v;
    }
  }
}

// Sharded offsets: per bucket, sum 8 shard counts -> total; block scan + cursor;
// emit offs, cnt_tot, and per-shard bases. TN%256==0 -> no tail.
__global__ void k_offsets_sh(const int* __restrict__ cnt_s, int* __restrict__ offs,
                             int* __restrict__ cnt_tot, int* __restrict__ sbase,
                             int* __restrict__ cursor) {
  __shared__ int s[256];
  __shared__ int base;
  int tid = threadIdx.x;
  int i = blockIdx.x * 256 + tid;
  int c[8];
  int tot = 0;
#pragma unroll
  for (int k = 0; k < 8; ++k) { c[k] = cnt_s[k * TN + i]; tot += c[k]; }
  s[tid] = tot;
  __syncthreads();
  for (int d2 = 1; d2 < 256; d2 <<= 1) {
    int v = (tid >= d2) ? s[tid - d2] : 0;
    __syncthreads();
    s[tid] += v;
    __syncthreads();
  }
  if (tid == 255) base = atomicAdd(cursor, s[255]);
  __syncthreads();
  int a = base + s[tid] - tot;  // exclusive
  offs[i] = a;
  cnt_tot[i] = tot;
#pragma unroll
  for (int k = 0; k < 8; ++k) { sbase[k * TN + i] = a; a += c[k]; }
}

// Sharded scatter: pos = sbase[shard][bucket] + local_rank.
__global__ void k_scatter_sh(const int* __restrict__ src, const int* __restrict__ dst,
                             const int* __restrict__ sbase,
                             const int* __restrict__ rank, int* __restrict__ eid) {
  int i0 = (blockIdx.x * 256 + threadIdx.x) * 4;
  if (i0 >= T * E) return;
  const int tb = (i0 / E) * N;
  int4 sv = *(const int4*)(src + i0);
  int4 d  = *(const int4*)(dst + i0);
  int4 rp = *(const int4*)(rank + i0);
  {
    unsigned u = (unsigned)rp.x;
    eid[sbase[(u >> 28) * TN + tb + d.x] + (int)(u & 0x0FFFFFFFu)] = sv.x;
  }
  {
    unsigned u = (unsigned)rp.y;
    eid[sbase[(u >> 28) * TN + tb + d.y] + (int)(u & 0x0FFFFFFFu)] = sv.y;
  }
  {
    unsigned u = (unsigned)rp.z;
    eid[sbase[(u >> 28) * TN + tb + d.z] + (int)(u & 0x0FFFFFFFu)] = sv.z;
  }
  {
    unsigned u = (unsigned)rp.w;
    eid[sbase[(u >> 28) * TN + tb + d.w] + (int)(u & 0x0FFFFFFFu)] = sv.w;
  }
}

// ---------- fallback (v9) offsets/scatter ----------
__global__ void k_offsets(const int* __restrict__ cnt, int* __restrict__ offs,
                          int* __restrict__ cursor) {
  __shared__ int s[256];
  __shared__ int base;
  int tid = threadIdx.x;
  int i = blockIdx.x * 256 + tid;
  int c = (i < TN) ? cnt[i] : 0;
  s[tid] = c;
  __syncthreads();
  for (int d = 1; d < 256; d <<= 1) {
    int v = (tid >= d) ? s[tid - d] : 0;
    __syncthreads();
    s[tid] += v;
    __syncthreads();
  }
  if (tid == 255) base = atomicAdd(cursor, s[255]);
  __syncthreads();
  if (i < TN) offs[i] = base + s[tid] - c;
}

__global__ void k_scatter(const int* __restrict__ src, const int* __restrict__ dst,
                          const int* __restrict__ offs, const int* __restrict__ rank,
                          int* __restrict__ eid) {
  int i0 = (blockIdx.x * 256 + threadIdx.x) * 4;
  if (i0 >= T * E) return;
  const int tb = (i0 / E) * N;
  int4 s = *(const int4*)(src + i0);
  int4 d = *(const int4*)(dst + i0);
  int4 r = *(const int4*)(rank + i0);
  eid[offs[tb + d.x] + r.x] = s.x;
  eid[offs[tb + d.y] + r.y] = s.y;
  eid[offs[tb + d.z] + r.z] = s.z;
  eid[offs[tb + d.w] + r.w] = s.w;
}

// Fused aggregate + bf16 MFMA GEMM (v3 core; gather 2-deep pipelined).
// 256 threads (4 waves), 64-node tile. LDS 52224 B -> 3 blocks/CU.
template <bool XB>
__global__ __launch_bounds__(256, 3) void k_fused(
    const float* __restrict__ x, const __bf16* __restrict__ xb,
    const __bf16* __restrict__ wt, const float* __restrict__ b,
    const float* __restrict__ bself, const int* __restrict__ cnt,
    const int* __restrict__ offs, const int* __restrict__ eid,
    float* __restrict__ out) {
  __shared__ __align__(16) __bf16 a_s[NT * AS];
  __shared__ __align__(16) __bf16 w_s[D * AS];

  const int tid  = threadIdx.x;
  const int nb   = blockIdx.x * NT;
  const int wv   = tid >> 6;
  const int lane = tid & 63;
  const int quad = lane >> 4;
  const int l16  = lane & 15;
  const int ln   = tid >> 2;   // staging node 0..63
  const int q    = tid & 3;    // staging k-quarter

  f32x4 acc[8];
#pragma unroll
  for (int ct = 0; ct < 8; ++ct) acc[ct] = (f32x4){0.f, 0.f, 0.f, 0.f};

  for (int pass = 0; pass < 5; ++pass) {
    const bool self = (pass == 4);

    // ---- stage w_s (issue first; overlaps gather latency)
    {
      const __bf16* wsrc = wt + pass * D * D;
#pragma unroll
      for (int c = 0; c < 8; ++c) {
        int idx  = c * 256 + tid;
        int row  = idx >> 4;
        int col8 = (idx & 15) * 8;
        *(bf16x8*)(w_s + row * AS + col8) = *(const bf16x8*)(wsrc + row * D + col8);
      }
    }

    // ---- stage a_s: mean-aggregated features (skipped for self-pass when XB)
    if (!(XB && self)) {
      float r[32];
#pragma unroll
      for (int i = 0; i < 32; ++i) r[i] = 0.f;
      const int node = nb + ln;
      if (self) {  // only reached when !XB
        const float4* xr = (const float4*)(x + (size_t)node * D + q * 32);
#pragma unroll
        for (int i = 0; i < 8; ++i) {
          float4 v = xr[i];
          r[4 * i] = v.x; r[4 * i + 1] = v.y; r[4 * i + 2] = v.z; r[4 * i + 3] = v.w;
        }
      } else {
        const int deg  = cnt[pass * N + node];
        const int base = offs[pass * N + node];
        if (XB) {
          if (deg > 0) {
            // 2-deep pipeline: rows of edge e+1 load while edge e accumulates.
            int nxt = eid[base];
            const bf16x8* xr = (const bf16x8*)(xb + (size_t)nxt * D + q * 32);
            bf16x8 v0 = xr[0], v1 = xr[1], v2 = xr[2], v3 = xr[3];
            for (int e = 0; e < deg; ++e) {
              bf16x8 w0, w1, w2, w3;
              if (e + 1 < deg) {
                int nx2 = eid[base + e + 1];
                const bf16x8* x2 = (const bf16x8*)(xb + (size_t)nx2 * D + q * 32);
                w0 = x2[0]; w1 = x2[1]; w2 = x2[2]; w3 = x2[3];
              } else {
                w0 = v0; w1 = v1; w2 = v2; w3 = v3;
              }
#pragma unroll
              for (int j = 0; j < 8; ++j) {
                r[j]      += (float)v0[j];
                r[8 + j]  += (float)v1[j];
                r[16 + j] += (float)v2[j];
                r[24 + j] += (float)v3[j];
              }
              v0 = w0; v1 = w1; v2 = w2; v3 = w3;
            }
          }
        } else {
          for (int e = 0; e < deg; ++e) {
            const int sidx = eid[base + e];
            const float4* xr = (const float4*)(x + (size_t)sidx * D + q * 32);
#pragma unroll
            for (int i = 0; i < 8; ++i) {
              float4 v = xr[i];
              r[4 * i] += v.x; r[4 * i + 1] += v.y;
              r[4 * i + 2] += v.z; r[4 * i + 3] += v.w;
            }
          }
        }
        const float inv = (deg > 0) ? (1.0f / (float)deg) : 0.0f;
#pragma unroll
        for (int i = 0; i < 32; ++i) r[i] *= inv;
      }
      __bf16* arow = a_s + ln * AS + q * 32;
#pragma unroll
      for (int g = 0; g < 4; ++g) {
        bf16x8 v;
#pragma unroll
        for (int j = 0; j < 8; ++j) v[j] = (__bf16)r[8 * g + j];
        *(bf16x8*)(arow + g * 8) = v;
      }
    }
    __syncthreads();

    // ---- MFMA: acc[16 x 128 per wave] += A @ W^T-layout
#pragma unroll
    for (int ks = 0; ks < 4; ++ks) {
      bf16x8 af;
      if (XB && self) {
        af = *(const bf16x8*)(xb + (size_t)(nb + 16 * wv + l16) * D + ks * 32 +
                              quad * 8);
      } else {
        af = *(const bf16x8*)(a_s + (16 * wv + l16) * AS + ks * 32 + quad * 8);
      }
#pragma unroll
      for (int ct = 0; ct < 8; ++ct) {
        bf16x8 bfr = *(const bf16x8*)(w_s + (16 * ct + l16) * AS + ks * 32 + quad * 8);
        acc[ct] = __builtin_amdgcn_mfma_f32_16x16x32_bf16(af, bfr, acc[ct], 0, 0, 0);
      }
    }

    // ---- bias: b[t] gated on deg>0 per output row; b_self unconditional.
    {
      const float* bt = self ? bself : (b + pass * D);
      bool rowon[4];
#pragma unroll
      for (int r = 0; r < 4; ++r) {
        rowon[r] = self ? true : (cnt[pass * N + nb + 16 * wv + quad * 4 + r] > 0);
      }
#pragma unroll
      for (int ct = 0; ct < 8; ++ct) {
        float bv = bt[16 * ct + l16];
#pragma unroll
        for (int r = 0; r < 4; ++r)
          if (rowon[r]) acc[ct][r] += bv;
      }
    }
    if (pass < 4) __syncthreads();  // guard LDS overwrite by next pass
  }

  // ---- epilogue
#pragma unroll
  for (int ct = 0; ct < 8; ++ct) {
#pragma unroll
    for (int r = 0; r < 4; ++r) {
      out[(size_t)(nb + 16 * wv + quad * 4 + r) * D + 16 * ct + l16] = acc[ct][r];
    }
  }
}

}  // namespace

extern "C" void kernel_launch(void* const* d_in, const int* in_sizes, int n_in,
                              void* d_out, int out_size, void* d_ws, size_t ws_size,
                              hipStream_t stream) {
  const float* x     = (const float*)d_in[0];
  const float* W     = (const float*)d_in[1];
  const float* b     = (const float*)d_in[2];
  const float* Wself = (const float*)d_in[3];
  const float* bself = (const float*)d_in[4];
  const int*   src   = (const int*)d_in[5];
  const int*   dst   = (const int*)d_in[6];
  float* out = (float*)d_out;

  // sharded ws (ints): cnt_s[8*TN] | cursor[4] | offs[TN] | cnt_tot[TN] |
  //                    sbase[8*TN] | eid[T*E] | rank[T*E] | wt bf16 | xb bf16
  const size_t need_sh =
      (size_t)(8 * TN + 4 + TN + TN + 8 * TN + T * E + T * E) * 4 +
      (size_t)5 * D * D * 2 + (size_t)N * D * 2;  // ~125 MB (ws >= 157MB proven)
  // v9 fallback ws
  const size_t need_fb =
      (size_t)(TN + 4 + TN + T * E + T * E) * 4 + (size_t)5 * D * D * 2 +
      (size_t)N * D * 2;  // ~74 MB

  if (ws_size >= need_sh) {
    int* cnt_s  = (int*)d_ws;
    int* cursor = cnt_s + 8 * TN;
    int* offs   = cursor + 4;
    int* cnt_t  = offs + TN;
    int* sbase  = cnt_t + TN;
    int* eid    = sbase + 8 * TN;
    int* rank   = eid + T * E;  // slack for eid's +1 prefetch read
    __bf16* wt  = (__bf16*)(rank + T * E);
    __bf16* xb  = wt + 5 * D * D;

    hipMemsetAsync(cnt_s, 0, (size_t)(8 * TN + 4) * 4, stream);
    k_prep<true><<<CNT_B + PX_B + PW_B, 256, 0, stream>>>(dst, cnt_s, rank, x, xb,
                                                          W, Wself, wt);
    k_offsets_sh<<<TN / 256, 256, 0, stream>>>(cnt_s, offs, cnt_t, sbase, cursor);
    k_scatter_sh<<<CNT_B, 256, 0, stream>>>(src, dst, sbase, rank, eid);
    k_fused<true><<<N / NT, 256, 0, stream>>>(x, xb, wt, b, bself, cnt_t, offs,
                                              eid, out);
    return;
  }

  // ---- v9 fallback ----
  int* cnt    = (int*)d_ws;
  int* cursor = cnt + TN;
  int* offs   = cursor + 4;
  int* eid    = offs + TN;
  int* rank   = eid + T * E;
  __bf16* wt  = (__bf16*)(rank + T * E);
  __bf16* xb  = wt + 5 * D * D;
  (void)need_fb;

  hipMemsetAsync(cnt, 0, (size_t)(TN + 4) * 4, stream);
  k_prep<false><<<CNT_B + PX_B + PW_B, 256, 0, stream>>>(dst, cnt, rank, x, xb,
                                                         W, Wself, wt);
  k_offsets<<<(TN + 255) / 256, 256, 0, stream>>>(cnt, offs, cursor);
  k_scatter<<<CNT_B, 256, 0, stream>>>(src, dst, offs, rank, eid);
  k_fused<true><<<N / NT, 256, 0, stream>>>(x, xb, wt, b, bself, cnt, offs,
                                            eid, out);
}